// Round 7
// baseline (993.016 us; speedup 1.0000x reference)
//
#include <hip/hip_runtime.h>
#include <hip/hip_bf16.h>
#include <stdint.h>

#define TOKENS 512
#define HDIM   2048
#define IDIM   1408
#define SIDIM  5632
#define NEXP   60
#define TOPK   4
#define NSLOTS (TOKENS*TOPK)   /* 2048 */
#define ROWPAD 64

// counted-vmcnt (T4): in-order ledger, never drain mid-loop
#define VMWAIT(N) asm volatile("s_waitcnt vmcnt(" #N ")" ::: "memory")

typedef __attribute__((ext_vector_type(8))) short bf16x8;
typedef __attribute__((ext_vector_type(4))) float f32x4;

__device__ __forceinline__ short f2bf(float f){
  uint32_t u = __float_as_uint(f);
  u = (u + 0x7fffu + ((u >> 16) & 1u)) >> 16;   // RNE
  return (short)(u & 0xffffu);
}

__device__ __forceinline__ bf16x8 pack8(float4 a, float4 b){
  bf16x8 r;
  r[0]=f2bf(a.x); r[1]=f2bf(a.y); r[2]=f2bf(a.z); r[3]=f2bf(a.w);
  r[4]=f2bf(b.x); r[5]=f2bf(b.y); r[6]=f2bf(b.z); r[7]=f2bf(b.w);
  return r;
}

__device__ __forceinline__ f32x4 zero4(){
  f32x4 z; z[0]=0.f; z[1]=0.f; z[2]=0.f; z[3]=0.f; return z;
}

__device__ __forceinline__ f32x4 mfma16(bf16x8 a, bf16x8 b, f32x4 c){
  return __builtin_amdgcn_mfma_f32_16x16x32_bf16(a, b, c, 0, 0, 0);
}

// ==== wave-private W chunk stage: 16 rows x 128 fp32, 512B contiguous/row ====
// 8 instructions; instr i = one 1KB contiguous run over rows (2i, 2i+1).
// LDS slot s = i*64 + lane; row(s)=s>>5, phys unit = s&31 holds logical unit
// (pu - row)&31 (rotation rides on the per-lane GLOBAL src; LDS dest linear).
__device__ __forceinline__ void stage_chunk(float4* buf, const float* __restrict__ Wr,
                                            int K, int k0, int lane){
  #pragma unroll
  for (int i=0;i<8;i++){
    int r  = 2*i + (lane>>5);
    int pu = lane & 31;
    int lu = (pu - r) & 31;
    const float* src = Wr + (size_t)r*K + k0 + lu*4;
    __builtin_amdgcn_global_load_lds(
        (const __attribute__((address_space(1))) void*)src,
        (__attribute__((address_space(3))) void*)(buf + i*64), 16, 0, 0);
  }
}

// B-frag read: row c16, seg j, k-quarter kq -> logical units j*8+2kq, +1.
// bank group = (j*8+2kq+c16)&7: 8 lanes/group, distinct addrs => conflict-free
__device__ __forceinline__ bf16x8 rdW(const float4* buf, int c16, int kq, int j){
  const float4* row = buf + c16*32;
  float4 f0 = row[(j*8 + 2*kq     + c16) & 31];
  float4 f1 = row[(j*8 + 2*kq + 1 + c16) & 31];
  return pack8(f0, f1);
}

// ==== barrier-free wave GEMM item: 64-col x-tile (this wave: 16 cols) ========
// per chunk: [A 16 loads][stage W_{c+1}: 8][VMWAIT(8) => A_c,W_c done,
// W_{c+1} in flight][4 segs x {2 ds_read, 4 MFMA}]. No s_barrier anywhere.
__device__ __forceinline__ void gemm_item(
    const float* __restrict__ Wt,    // W base of x-tile (row bx*64), stride K
    const short* __restrict__ Abase, // bf16 A rows, stride K
    int K, int NO, int col,          // output stride, this lane's output col
    int m_start, int m_end,
    void* __restrict__ outp, int out_f32,
    float4* wbuf /* 2 x 512 float4 */, int wv, int lane)
{
  if (m_start >= m_end) return;
  int c16 = lane & 15, kq = lane >> 4;
  int nc = K >> 7;                               // chunks of 128 floats
  const float* Wr = Wt + (size_t)(wv*16)*K;      // this wave's 16 rows

  for (int m0 = m_start; m0 < m_end; m0 += 64){
    int mrem = m_end - m0;
    const short* Ar = Abase + (size_t)m0*K;
    f32x4 acc[4];
    #pragma unroll
    for (int i=0;i<4;i++) acc[i] = zero4();

    float4* cur = wbuf;
    float4* nxt = wbuf + 512;
    stage_chunk(cur, Wr, K, 0, lane);

    for (int c = 0; c < nc; ++c){
      int k0 = c << 7;
      // A fragments for this chunk (issued BEFORE next stage: in-order vmcnt)
      bf16x8 av[16];
      #pragma unroll
      for (int j=0;j<4;j++){
        #pragma unroll
        for (int mf=0; mf<4; mf++)
          av[j*4+mf] = *(const bf16x8*)(Ar + (size_t)(c16+16*mf)*K + k0 + j*32 + kq*8);
      }
      if (c+1 < nc){
        stage_chunk(nxt, Wr, K, k0+128, lane);
        VMWAIT(8);                 // A_c + W_c landed; W_{c+1} stays in flight
      } else {
        VMWAIT(0);
      }
      __builtin_amdgcn_sched_barrier(0);
      #pragma unroll
      for (int j=0;j<4;j++){
        bf16x8 b = rdW(cur, c16, kq, j);
        #pragma unroll
        for (int mf=0; mf<4; mf++)
          acc[mf] = mfma16(av[j*4+mf], b, acc[mf]);
      }
      float4* t = cur; cur = nxt; nxt = t;
    }

    #pragma unroll
    for (int mf=0; mf<4; mf++){
      #pragma unroll
      for (int j=0;j<4;j++){
        int mrow = mf*16 + kq*4 + j;             // D row=(lane>>4)*4+j (+16*mf)
        if (mrow < mrem){
          if (out_f32) ((float*)outp)[(size_t)(m0+mrow)*NO + col] = acc[mf][j];
          else         ((short*)outp)[(size_t)(m0+mrow)*NO + col] = f2bf(acc[mf][j]);
        }
      }
    }
  }
}

// ---------------- router ------------------------------------------------------
__global__ __launch_bounds__(64) void router_kernel(
    const float* __restrict__ x, const float* __restrict__ rw,
    const float* __restrict__ egw, int* __restrict__ topk_idx,
    float* __restrict__ topk_w, float* __restrict__ gates,
    int* __restrict__ counts)
{
  int t = blockIdx.x;
  int lane = threadIdx.x;
  const float* xr = x + (size_t)t*HDIM;
  float xv[HDIM/64];
  #pragma unroll
  for (int i=0;i<HDIM/64;i++) xv[i] = xr[lane + 64*i];

  float mylogit = -1e30f;
  for (int e=0;e<NEXP;e++){
    const float* w = rw + (size_t)e*HDIM;
    float acc = 0.f;
    #pragma unroll
    for (int i=0;i<HDIM/64;i++) acc += xv[i]*w[lane+64*i];
    #pragma unroll
    for (int s=32;s>0;s>>=1) acc += __shfl_xor(acc, s);
    if (lane == e) mylogit = acc;
  }
  {
    float acc = 0.f;
    #pragma unroll
    for (int i=0;i<HDIM/64;i++) acc += xv[i]*egw[lane+64*i];
    #pragma unroll
    for (int s=32;s>0;s>>=1) acc += __shfl_xor(acc, s);
    if (lane == 0) gates[t] = 1.f/(1.f + __expf(-acc));
  }
  float m = mylogit;
  #pragma unroll
  for (int s=32;s>0;s>>=1) m = fmaxf(m, __shfl_xor(m, s));
  float p = (lane < NEXP) ? __expf(mylogit - m) : 0.f;
  float sum = p;
  #pragma unroll
  for (int s=32;s>0;s>>=1) sum += __shfl_xor(sum, s);
  float prob = p / sum;
  for (int k=0;k<TOPK;k++){
    float v = prob; int idx = lane;
    #pragma unroll
    for (int s=32;s>0;s>>=1){
      float ov = __shfl_xor(v, s); int oi = __shfl_xor(idx, s);
      if (ov > v || (ov == v && oi < idx)){ v = ov; idx = oi; }
    }
    if (lane == 0){
      topk_idx[t*TOPK+k] = idx;
      topk_w[t*TOPK+k]  = v;
      atomicAdd(&counts[idx], 1);
    }
    if (lane == idx) prob = -1e30f;
  }
}

__global__ void prefix_kernel(const int* __restrict__ counts, int* __restrict__ offsets)
{
  if (threadIdx.x == 0){
    int acc = 0;
    for (int e=0;e<NEXP;e++){ offsets[e] = acc; acc += counts[e]; }
    offsets[NEXP] = acc;
  }
}

__global__ __launch_bounds__(256) void scatter_kernel(
    const float* __restrict__ x, const int* __restrict__ topk_idx,
    const int* __restrict__ offsets, int* __restrict__ fill,
    int* __restrict__ slot_of, __hip_bfloat16* __restrict__ xg,
    __hip_bfloat16* __restrict__ xb)
{
  int t = blockIdx.x, tid = threadIdx.x;
  __shared__ int sl[TOPK];
  if (tid == 0){
    for (int k=0;k<TOPK;k++){
      int e = topk_idx[t*TOPK+k];
      int pos = atomicAdd(&fill[e], 1);
      int s = offsets[e] + pos;
      slot_of[t*TOPK+k] = s;
      sl[k] = s;
    }
  }
  __syncthreads();
  const float4* xr = (const float4*)(x + (size_t)t*HDIM);
  float4 v0 = xr[tid*2], v1 = xr[tid*2+1];
  bf16x8 b = pack8(v0, v1);
  *(bf16x8*)((short*)xb + (size_t)t*HDIM + tid*8) = b;
  #pragma unroll
  for (int k=0;k<TOPK;k++)
    *(bf16x8*)((short*)xg + (size_t)sl[k]*HDIM + tid*8) = b;
}

// ==== gate/up launch: 4048 blocks = 8 XCD x (88 shG + 88 shU + 330 expert) ===
__global__ __launch_bounds__(256) void gu_kernel(
    const float* __restrict__ gw, const float* __restrict__ uw,
    const float* __restrict__ sgw, const float* __restrict__ suw,
    const short* __restrict__ xg, const short* __restrict__ xb,
    short* __restrict__ act_g, short* __restrict__ act_u,
    short* __restrict__ shact_g, short* __restrict__ shact_u,
    const int* __restrict__ offsets)
{
  extern __shared__ __align__(16) char smem[];   // 64 KB: 4 waves x 16 KB
  int bid = blockIdx.x;
  int xcd = bid & 7, pos = bid >> 3;

  const float* W; const short* A; short* outp;
  int NO, bx, m_start, m_end;
  if (pos < 176){                                // shared expert (heavy: first)
    int mat = pos >= 88;
    int idx = xcd*88 + (pos - (mat ? 88 : 0));
    bx = idx % 88;
    int mt = idx / 88;
    W = mat ? suw : sgw; A = xb; outp = mat ? shact_u : shact_g;
    NO = SIDIM; m_start = mt*64; m_end = m_start + 64;
  } else {
    int qq = xcd*330 + (pos - 176);
    int e = qq / 44, rem = qq % 44;
    int mat = rem >= 22;
    bx = mat ? rem - 22 : rem;
    size_t wo = (size_t)e * IDIM * HDIM;
    W = (mat ? uw : gw) + wo;
    A = xg; outp = mat ? act_u : act_g;
    NO = IDIM; m_start = offsets[e]; m_end = offsets[e+1];
  }
  int tid = threadIdx.x, wv = tid >> 6, lane = tid & 63;
  float4* wbuf = (float4*)(smem + wv*16384);
  int col = bx*64 + wv*16 + (lane & 15);
  gemm_item(W + (size_t)(bx*64)*HDIM, A, HDIM, NO, col,
            m_start, m_end, outp, 0, wbuf, wv, lane);
}

// ==== silu join: act = silu(g)*u (expert 2048x1408 + shared 512x5632) ========
#define JEXP (NSLOTS*(IDIM/8))        /* 360448 short8 units */
#define JTOT (JEXP + TOKENS*(SIDIM/8))/* 720896 */
__global__ __launch_bounds__(256) void join_kernel(
    const short* __restrict__ act_g, const short* __restrict__ act_u,
    short* __restrict__ act,
    const short* __restrict__ shact_g, const short* __restrict__ shact_u,
    short* __restrict__ shact)
{
  int id = blockIdx.x*256 + threadIdx.x;
  const short *gp, *up; short* op;
  if (id < JEXP){
    gp = act_g + (size_t)id*8; up = act_u + (size_t)id*8; op = act + (size_t)id*8;
  } else {
    size_t o = (size_t)(id - JEXP)*8;
    gp = shact_g + o; up = shact_u + o; op = shact + o;
  }
  bf16x8 g8 = *(const bf16x8*)gp;
  bf16x8 u8 = *(const bf16x8*)up;
  bf16x8 r;
  #pragma unroll
  for (int i=0;i<8;i++){
    float g = __uint_as_float(((uint32_t)(uint16_t)g8[i]) << 16);
    float u = __uint_as_float(((uint32_t)(uint16_t)u8[i]) << 16);
    r[i] = f2bf(g * u / (1.f + __expf(-g)));
  }
  *(bf16x8*)op = r;
}

// ==== down launch: 2176 blocks = 8 XCD x (32 shared + 240 expert) ============
__global__ __launch_bounds__(256) void down_kernel(
    const float* __restrict__ dw, const float* __restrict__ sdw,
    const short* __restrict__ act, const short* __restrict__ shact,
    float* __restrict__ dslot, float* __restrict__ shdown,
    const int* __restrict__ offsets)
{
  extern __shared__ __align__(16) char smem[];
  int bid = blockIdx.x;
  int xcd = bid & 7, pos = bid >> 3;

  const float* W; const short* A; float* outp;
  int K, bx, m_start, m_end;
  if (pos < 32){                                 // shared (K=5632: heavy, first)
    int idx = xcd*32 + pos;
    bx = idx & 31; int mt = idx >> 5;
    W = sdw; A = shact; outp = shdown; K = SIDIM;
    m_start = mt*64; m_end = m_start + 64;
  } else {
    int qq = xcd*240 + (pos - 32);
    int e = qq >> 5; bx = qq & 31;
    W = dw + (size_t)e * HDIM * IDIM;
    A = act; outp = dslot; K = IDIM;
    m_start = offsets[e]; m_end = offsets[e+1];
  }
  int tid = threadIdx.x, wv = tid >> 6, lane = tid & 63;
  float4* wbuf = (float4*)(smem + wv*16384);
  int col = bx*64 + wv*16 + (lane & 15);
  gemm_item(W + (size_t)(bx*64)*K, A, K, HDIM, col,
            m_start, m_end, outp, 1, wbuf, wv, lane);
}

// ---------------- final combine ----------------------------------------------
__global__ __launch_bounds__(256) void combine_kernel(
    const float* __restrict__ dslot, const float* __restrict__ shdown,
    const int* __restrict__ slot_of, const float* __restrict__ topw,
    const float* __restrict__ gates, float* __restrict__ out)
{
  int t = blockIdx.x, tid = threadIdx.x;
  int4  sl = ((const int4*)slot_of)[t];
  float4 w = ((const float4*)topw)[t];
  float sg = gates[t];
  const float* r0 = dslot + (size_t)sl.x*HDIM;
  const float* r1 = dslot + (size_t)sl.y*HDIM;
  const float* r2 = dslot + (size_t)sl.z*HDIM;
  const float* r3 = dslot + (size_t)sl.w*HDIM;
  const float* rs = shdown + (size_t)t*HDIM;
  float* o = out + (size_t)t*HDIM;
  #pragma unroll
  for (int it=0; it<HDIM/(256*4); ++it){
    int h = (tid + it*256) * 4;
    float4 a0 = *(const float4*)(r0+h);
    float4 a1 = *(const float4*)(r1+h);
    float4 a2 = *(const float4*)(r2+h);
    float4 a3 = *(const float4*)(r3+h);
    float4 as = *(const float4*)(rs+h);
    float4 r;
    r.x = w.x*a0.x + w.y*a1.x + w.z*a2.x + w.w*a3.x + sg*as.x;
    r.y = w.x*a0.y + w.y*a1.y + w.z*a2.y + w.w*a3.y + sg*as.y;
    r.z = w.x*a0.z + w.y*a1.z + w.z*a2.z + w.w*a3.z + sg*as.z;
    r.w = w.x*a0.w + w.y*a1.w + w.z*a2.w + w.w*a3.w + sg*as.w;
    *(float4*)(o+h) = r;
  }
}

extern "C" void kernel_launch(void* const* d_in, const int* in_sizes, int n_in,
                              void* d_out, int out_size, void* d_ws, size_t ws_size,
                              hipStream_t stream)
{
  const float* x   = (const float*)d_in[0];
  const float* rw  = (const float*)d_in[1];
  const float* gw  = (const float*)d_in[2];
  const float* uw  = (const float*)d_in[3];
  const float* dw  = (const float*)d_in[4];
  const float* sgw = (const float*)d_in[5];
  const float* suw = (const float*)d_in[6];
  const float* sdw = (const float*)d_in[7];
  const float* egw = (const float*)d_in[8];

  char* p = (char*)d_ws;
  auto alloc = [&](size_t bytes)->char*{
    char* r = p; p += (bytes + 255) & ~(size_t)255; return r;
  };
  int*   counts   = (int*)  alloc(NEXP*4);
  int*   fill     = (int*)  alloc(NEXP*4);
  int*   offsets  = (int*)  alloc((NEXP+1)*4);
  int*   topk_idx = (int*)  alloc(NSLOTS*4);
  float* topk_w   = (float*)alloc(NSLOTS*4);
  int*   slot_of  = (int*)  alloc(NSLOTS*4);
  float* gates    = (float*)alloc(TOKENS*4);
  short* xb      = (short*)alloc((size_t)TOKENS*HDIM*2);
  short* xg      = (short*)alloc((size_t)(NSLOTS+ROWPAD)*HDIM*2);
  short* act_g   = (short*)alloc((size_t)(NSLOTS+ROWPAD)*IDIM*2);
  short* act_u   = (short*)alloc((size_t)(NSLOTS+ROWPAD)*IDIM*2);
  short* act     = (short*)alloc((size_t)(NSLOTS+ROWPAD)*IDIM*2);
  short* shact_g = (short*)alloc((size_t)TOKENS*SIDIM*2);
  short* shact_u = (short*)alloc((size_t)TOKENS*SIDIM*2);
  short* shact   = (short*)alloc((size_t)TOKENS*SIDIM*2);
  float* dslot   = (float*)alloc((size_t)NSLOTS*HDIM*4);
  float* shdown  = (float*)alloc((size_t)TOKENS*HDIM*4);
  if ((size_t)(p - (char*)d_ws) > ws_size) return;  // ws too small: fail loudly

  hipMemsetAsync(counts, 0, NEXP*4, stream);
  hipMemsetAsync(fill,   0, NEXP*4, stream);

  router_kernel <<<TOKENS, 64, 0, stream>>>(x, rw, egw, topk_idx, topk_w, gates, counts);
  prefix_kernel <<<1, 64, 0, stream>>>(counts, offsets);
  scatter_kernel<<<TOKENS, 256, 0, stream>>>(x, topk_idx, offsets, fill, slot_of,
                                             (__hip_bfloat16*)xg, (__hip_bfloat16*)xb);

  gu_kernel  <<<4048, 256, 64*1024, stream>>>(gw, uw, sgw, suw, xg, xb,
                                              act_g, act_u, shact_g, shact_u, offsets);
  join_kernel<<<JTOT/256, 256, 0, stream>>>(act_g, act_u, act, shact_g, shact_u, shact);
  down_kernel<<<2176, 256, 64*1024, stream>>>(dw, sdw, act, shact, dslot, shdown, offsets);

  combine_kernel<<<TOKENS, 256, 0, stream>>>(dslot, shdown, slot_of, topk_w, gates,
                                             (float*)d_out);
}

// Round 8
// 746.591 us; speedup vs baseline: 1.3301x; 1.3301x over previous
//
#include <hip/hip_runtime.h>
#include <hip/hip_bf16.h>
#include <stdint.h>

#define TOKENS 512
#define HDIM   2048
#define IDIM   1408
#define SIDIM  5632
#define NEXP   60
#define TOPK   4
#define NSLOTS (TOKENS*TOPK)   /* 2048 */
#define ROWPAD 64

// counted-vmcnt barrier primitives (T3/T4): raw s_barrier, NO vmcnt(0) drain
#define VMWAIT(N) asm volatile("s_waitcnt vmcnt(" #N ")" ::: "memory")
#define SBAR()    asm volatile("s_barrier" ::: "memory")

typedef __attribute__((ext_vector_type(8))) short bf16x8;
typedef __attribute__((ext_vector_type(4))) float f32x4;

__device__ __forceinline__ short f2bf(float f){
  uint32_t u = __float_as_uint(f);
  u = (u + 0x7fffu + ((u >> 16) & 1u)) >> 16;   // RNE
  return (short)(u & 0xffffu);
}

__device__ __forceinline__ bf16x8 pack8(float4 a, float4 b){
  bf16x8 r;
  r[0]=f2bf(a.x); r[1]=f2bf(a.y); r[2]=f2bf(a.z); r[3]=f2bf(a.w);
  r[4]=f2bf(b.x); r[5]=f2bf(b.y); r[6]=f2bf(b.z); r[7]=f2bf(b.w);
  return r;
}

__device__ __forceinline__ bf16x8 as_bf16x8(float4 v){
  union { float4 f; bf16x8 b; } u; u.f = v; return u.b;
}

__device__ __forceinline__ f32x4 zero4(){
  f32x4 z; z[0]=0.f; z[1]=0.f; z[2]=0.f; z[3]=0.f; return z;
}

__device__ __forceinline__ f32x4 mfma16(bf16x8 a, bf16x8 b, f32x4 c){
  return __builtin_amdgcn_mfma_f32_16x16x32_bf16(a, b, c, 0, 0, 0);
}

// ================== K-step-32 staged tiles (rule #21 both-sides swizzle) =====
// W tile: 64 rows x 32 fp32 = 8 KB = [64][8] float4 units, units rotated by
// row&7 (physical pu holds logical (pu-row)&7). LDS dest linear (HW), the
// permutation rides on the per-lane GLOBAL src. 2 loads/thread.
// (measured R5: SQ_LDS_BANK_CONFLICT == 0 with this scheme)
__device__ __forceinline__ void stage_w32(float4* tile, const float* __restrict__ W,
                                          int K, int k0, int tid){
  int l = tid & 63, wv = tid >> 6;
  #pragma unroll
  for (int j=0;j<2;j++){
    int u0 = j*256 + wv*64;                 // wave-uniform
    int u  = u0 + l;
    int row = u >> 3;
    int lu  = ((u & 7) - (row & 7)) & 7;
    const float* src = W + (size_t)row*K + k0 + lu*4;
    __builtin_amdgcn_global_load_lds(
        (const __attribute__((address_space(1))) void*)src,
        (__attribute__((address_space(3))) void*)(tile + u0), 16, 0, 0);
  }
}

// one B-fragment (8 bf16 = k kq*8..+8 of row r)
__device__ __forceinline__ bf16x8 read_wfrag32(const float4* tile, int r, int kq){
  int rot = r & 7;
  const float4* row = tile + (size_t)r*8;
  float4 f0 = row[(2*kq     + rot) & 7];
  float4 f1 = row[(2*kq + 1 + rot) & 7];
  return pack8(f0, f1);
}

// A tile: 64 rows x 32 bf16 = 4 KB = [64][4] float4 units, rotated by row&3.
// 1 load/thread.
__device__ __forceinline__ void stage_a32(float4* tile, const short* __restrict__ Arows,
                                          int K, int k0, int tid){
  int l = tid & 63, wv = tid >> 6;
  int u0 = wv*64;
  int u  = u0 + l;
  int row = u >> 2;
  int lu  = ((u & 3) - (row & 3)) & 3;
  const short* src = Arows + (size_t)row*K + k0 + lu*8;
  __builtin_amdgcn_global_load_lds(
      (const __attribute__((address_space(1))) void*)src,
      (__attribute__((address_space(3))) void*)(tile + u0), 16, 0, 0);
}

__device__ __forceinline__ void read_afrag32(const float4* tile, int c16, int kq,
                                             bf16x8* av){
  #pragma unroll
  for (int mf=0; mf<4; mf++){
    int row = c16 + 16*mf;
    av[mf] = as_bf16x8(tile[(size_t)row*4 + ((kq + row) & 3)]);
  }
}

// ---------------- router ------------------------------------------------------
__global__ __launch_bounds__(64) void router_kernel(
    const float* __restrict__ x, const float* __restrict__ rw,
    const float* __restrict__ egw, int* __restrict__ topk_idx,
    float* __restrict__ topk_w, float* __restrict__ gates,
    int* __restrict__ counts)
{
  int t = blockIdx.x;
  int lane = threadIdx.x;
  const float* xr = x + (size_t)t*HDIM;
  float xv[HDIM/64];
  #pragma unroll
  for (int i=0;i<HDIM/64;i++) xv[i] = xr[lane + 64*i];

  float mylogit = -1e30f;
  for (int e=0;e<NEXP;e++){
    const float* w = rw + (size_t)e*HDIM;
    float acc = 0.f;
    #pragma unroll
    for (int i=0;i<HDIM/64;i++) acc += xv[i]*w[lane+64*i];
    #pragma unroll
    for (int s=32;s>0;s>>=1) acc += __shfl_xor(acc, s);
    if (lane == e) mylogit = acc;
  }
  {
    float acc = 0.f;
    #pragma unroll
    for (int i=0;i<HDIM/64;i++) acc += xv[i]*egw[lane+64*i];
    #pragma unroll
    for (int s=32;s>0;s>>=1) acc += __shfl_xor(acc, s);
    if (lane == 0) gates[t] = 1.f/(1.f + __expf(-acc));
  }
  float m = mylogit;
  #pragma unroll
  for (int s=32;s>0;s>>=1) m = fmaxf(m, __shfl_xor(m, s));
  float p = (lane < NEXP) ? __expf(mylogit - m) : 0.f;
  float sum = p;
  #pragma unroll
  for (int s=32;s>0;s>>=1) sum += __shfl_xor(sum, s);
  float prob = p / sum;
  for (int k=0;k<TOPK;k++){
    float v = prob; int idx = lane;
    #pragma unroll
    for (int s=32;s>0;s>>=1){
      float ov = __shfl_xor(v, s); int oi = __shfl_xor(idx, s);
      if (ov > v || (ov == v && oi < idx)){ v = ov; idx = oi; }
    }
    if (lane == 0){
      topk_idx[t*TOPK+k] = idx;
      topk_w[t*TOPK+k]  = v;
      atomicAdd(&counts[idx], 1);
    }
    if (lane == idx) prob = -1e30f;
  }
}

__global__ void prefix_kernel(const int* __restrict__ counts, int* __restrict__ offsets)
{
  if (threadIdx.x == 0){
    int acc = 0;
    for (int e=0;e<NEXP;e++){ offsets[e] = acc; acc += counts[e]; }
    offsets[NEXP] = acc;
  }
}

__global__ __launch_bounds__(256) void scatter_kernel(
    const float* __restrict__ x, const int* __restrict__ topk_idx,
    const int* __restrict__ offsets, int* __restrict__ fill,
    int* __restrict__ slot_of, __hip_bfloat16* __restrict__ xg,
    __hip_bfloat16* __restrict__ xb)
{
  int t = blockIdx.x, tid = threadIdx.x;
  __shared__ int sl[TOPK];
  if (tid == 0){
    for (int k=0;k<TOPK;k++){
      int e = topk_idx[t*TOPK+k];
      int pos = atomicAdd(&fill[e], 1);
      int s = offsets[e] + pos;
      slot_of[t*TOPK+k] = s;
      sl[k] = s;
    }
  }
  __syncthreads();
  const float4* xr = (const float4*)(x + (size_t)t*HDIM);
  float4 v0 = xr[tid*2], v1 = xr[tid*2+1];
  bf16x8 b = pack8(v0, v1);
  *(bf16x8*)((short*)xb + (size_t)t*HDIM + tid*8) = b;
  #pragma unroll
  for (int k=0;k<TOPK;k++)
    *(bf16x8*)((short*)xg + (size_t)sl[k]*HDIM + tid*8) = b;
}

// =============== combined gate+up GEMM (expert + shared in one grid) =========
// grid = 1672 blocks (8 XCDs x 209). per-XCD: pos<44 -> shared quarter
// (s=xcd*44+pos: col-tile s%88, token-quarter s/88 = 2 m-tiles, W streamed
// once per quarter -> shared W demand 4x total, concurrent readers L3-share),
// else expert q = xcd*165 + pos-44, e=q/22, bx=q%22 (same-expert contiguous).
// LDS 40 KB: G0,G1,U0,U1 (8 KB) + A0,A1 (4 KB) -> 4 blocks/CU.
// 5 global_load_lds per thread per 32-k phase -> VMWAIT(5).
__global__ __launch_bounds__(256, 4) void gateup_all(
    const float* __restrict__ gW_e, const float* __restrict__ uW_e,
    const __hip_bfloat16* __restrict__ A_e, __hip_bfloat16* __restrict__ out_e,
    const float* __restrict__ gW_s, const float* __restrict__ uW_s,
    const __hip_bfloat16* __restrict__ A_s, __hip_bfloat16* __restrict__ out_s,
    const int* __restrict__ offsets)
{
  extern __shared__ __align__(16) char smem[];
  float4* G0 = (float4*)smem;
  float4* G1 = G0 + 512;
  float4* U0 = G1 + 512;
  float4* U1 = U0 + 512;
  float4* A0 = U1 + 512;
  float4* A1 = A0 + 256;

  int bid = blockIdx.x;
  int xcd = bid & 7, pos = bid >> 3;
  const float *Wg, *Wu; const short *Abase; short *outp;
  int NI, bx, m_start, m_end;
  if (pos < 44){                       // shared expert quarter (heavy: first)
    int s = xcd*44 + pos;
    bx = s % 88;
    int qt = s / 88;                   // 0..3
    Wg = gW_s; Wu = uW_s; Abase = (const short*)A_s; outp = (short*)out_s;
    NI = SIDIM;
    m_start = qt*128; m_end = m_start + 128;
  } else {                             // routed experts
    int q = xcd*165 + (pos - 44);
    int e = q/22; bx = q - e*22;
    size_t wo = (size_t)e * IDIM * HDIM;
    Wg = gW_e + wo; Wu = uW_e + wo;
    Abase = (const short*)A_e; outp = (short*)out_e;
    NI = IDIM;
    m_start = offsets[e]; m_end = offsets[e+1];
  }
  if (m_start >= m_end) return;
  const int K = HDIM;

  int tid  = threadIdx.x;
  int lane = tid & 63;
  int wv   = tid >> 6;
  int c16 = lane & 15, kq = lane >> 4;
  int wrow = bx*64 + wv*16 + c16;
  int r    = wv*16 + c16;
  const float* WgT = Wg + (size_t)(bx*64)*K;
  const float* WuT = Wu + (size_t)(bx*64)*K;

  for (int m0 = m_start; m0 < m_end; m0 += 64){
    int mrem = m_end - m0;
    const short* Ar = Abase + (size_t)m0*K;
    f32x4 accg[4], accu[4];
    #pragma unroll
    for (int i=0;i<4;i++){ accg[i] = zero4(); accu[i] = zero4(); }

    stage_w32(G0, WgT, K, 0, tid);
    stage_w32(U0, WuT, K, 0, tid);
    stage_a32(A0, Ar,  K, 0, tid);

    for (int k0 = 0; k0 < K; k0 += 64){
      stage_w32(G1, WgT, K, k0+32, tid);
      stage_w32(U1, WuT, K, k0+32, tid);
      stage_a32(A1, Ar,  K, k0+32, tid);
      VMWAIT(5); SBAR();
      {
        bf16x8 av[4];
        read_afrag32(A0, c16, kq, av);
        bf16x8 bg = read_wfrag32(G0, r, kq);
        bf16x8 bu = read_wfrag32(U0, r, kq);
        #pragma unroll
        for (int mf=0; mf<4; mf++){
          accg[mf] = mfma16(av[mf], bg, accg[mf]);
          accu[mf] = mfma16(av[mf], bu, accu[mf]);
        }
      }
      SBAR();
      if (k0 + 64 < K){
        stage_w32(G0, WgT, K, k0+64, tid);
        stage_w32(U0, WuT, K, k0+64, tid);
        stage_a32(A0, Ar,  K, k0+64, tid);
        VMWAIT(5);
      } else {
        VMWAIT(0);
      }
      SBAR();
      {
        bf16x8 av[4];
        read_afrag32(A1, c16, kq, av);
        bf16x8 bg = read_wfrag32(G1, r, kq);
        bf16x8 bu = read_wfrag32(U1, r, kq);
        #pragma unroll
        for (int mf=0; mf<4; mf++){
          accg[mf] = mfma16(av[mf], bg, accg[mf]);
          accu[mf] = mfma16(av[mf], bu, accu[mf]);
        }
      }
      SBAR();
    }

    #pragma unroll
    for (int mf=0; mf<4; mf++){
      #pragma unroll
      for (int j=0;j<4;j++){
        int mrow = mf*16 + kq*4 + j;
        if (mrow < mrem){
          float g = accg[mf][j], u = accu[mf][j];
          float s = g * u / (1.f + __expf(-g));
          outp[(size_t)(m0+mrow)*NI + wrow] = f2bf(s);
        }
      }
    }
  }
}

// =============== combined down GEMM (expert + shared in one grid) ============
// grid = 2048 blocks (8 x 256). per-XCD: pos<16 -> shared quarter
// (s=xcd*16+pos: col-tile s%32, token-quarter s/32; K=SIDIM, heavy: first),
// else expert q = xcd*240+pos-16, e=q/32.
// LDS 24 KB: W0,W1 (8 KB) + A0,A1 (4 KB). 3 loads/thread/phase -> VMWAIT(3).
__global__ __launch_bounds__(256, 4) void down_all(
    const float* __restrict__ W_e, const __hip_bfloat16* __restrict__ A_e,
    float* __restrict__ out_e,
    const float* __restrict__ W_s, const __hip_bfloat16* __restrict__ A_s,
    float* __restrict__ out_s,
    const int* __restrict__ offsets)
{
  extern __shared__ __align__(16) char smem[];
  float4* W0 = (float4*)smem;
  float4* W1 = W0 + 512;
  float4* A0 = W1 + 512;
  float4* A1 = A0 + 256;

  int bid = blockIdx.x;
  int xcd = bid & 7, pos = bid >> 3;
  const float* W; const short* Abase; float* outp;
  int K, bx, m_start, m_end;
  if (pos < 16){                       // shared expert quarter (long: first)
    int s = xcd*16 + pos;
    bx = s % 32;
    int qt = s / 32;                   // 0..3
    W = W_s; Abase = (const short*)A_s; outp = out_s; K = SIDIM;
    m_start = qt*128; m_end = m_start + 128;
  } else {
    int q = xcd*240 + (pos - 16);
    int e = q >> 5; bx = q & 31;
    W = W_e + (size_t)e * HDIM * IDIM;
    Abase = (const short*)A_e; outp = out_e; K = IDIM;
    m_start = offsets[e]; m_end = offsets[e+1];
  }
  if (m_start >= m_end) return;

  int tid  = threadIdx.x;
  int lane = tid & 63;
  int wv   = tid >> 6;
  int c16 = lane & 15, kq = lane >> 4;
  int wrow = bx*64 + wv*16 + c16;
  int r    = wv*16 + c16;
  const float* WT = W + (size_t)(bx*64)*K;

  for (int m0 = m_start; m0 < m_end; m0 += 64){
    int mrem = m_end - m0;
    const short* Ar = Abase + (size_t)m0*K;
    f32x4 acc[4];
    #pragma unroll
    for (int i=0;i<4;i++) acc[i] = zero4();

    stage_w32(W0, WT, K, 0, tid);
    stage_a32(A0, Ar, K, 0, tid);

    for (int k0 = 0; k0 < K; k0 += 64){
      stage_w32(W1, WT, K, k0+32, tid);
      stage_a32(A1, Ar, K, k0+32, tid);
      VMWAIT(3); SBAR();
      {
        bf16x8 av[4];
        read_afrag32(A0, c16, kq, av);
        bf16x8 b = read_wfrag32(W0, r, kq);
        #pragma unroll
        for (int mf=0; mf<4; mf++)
          acc[mf] = mfma16(av[mf], b, acc[mf]);
      }
      SBAR();
      if (k0 + 64 < K){
        stage_w32(W0, WT, K, k0+64, tid);
        stage_a32(A0, Ar, K, k0+64, tid);
        VMWAIT(3);
      } else {
        VMWAIT(0);
      }
      SBAR();
      {
        bf16x8 av[4];
        read_afrag32(A1, c16, kq, av);
        bf16x8 b = read_wfrag32(W1, r, kq);
        #pragma unroll
        for (int mf=0; mf<4; mf++)
          acc[mf] = mfma16(av[mf], b, acc[mf]);
      }
      SBAR();
    }

    #pragma unroll
    for (int mf=0; mf<4; mf++){
      #pragma unroll
      for (int j=0;j<4;j++){
        int mrow = mf*16 + kq*4 + j;
        if (mrow < mrem)
          outp[(size_t)(m0+mrow)*HDIM + wrow] = acc[mf][j];
      }
    }
  }
}

// ---------------- final combine ----------------------------------------------
__global__ __launch_bounds__(256) void combine_kernel(
    const float* __restrict__ dslot, const float* __restrict__ shdown,
    const int* __restrict__ slot_of, const float* __restrict__ topw,
    const float* __restrict__ gates, float* __restrict__ out)
{
  int t = blockIdx.x, tid = threadIdx.x;
  int4  sl = ((const int4*)slot_of)[t];
  float4 w = ((const float4*)topw)[t];
  float sg = gates[t];
  const float* r0 = dslot + (size_t)sl.x*HDIM;
  const float* r1 = dslot + (size_t)sl.y*HDIM;
  const float* r2 = dslot + (size_t)sl.z*HDIM;
  const float* r3 = dslot + (size_t)sl.w*HDIM;
  const float* rs = shdown + (size_t)t*HDIM;
  float* o = out + (size_t)t*HDIM;
  #pragma unroll
  for (int it=0; it<HDIM/(256*4); ++it){
    int h = (tid + it*256) * 4;
    float4 a0 = *(const float4*)(r0+h);
    float4 a1 = *(const float4*)(r1+h);
    float4 a2 = *(const float4*)(r2+h);
    float4 a3 = *(const float4*)(r3+h);
    float4 as = *(const float4*)(rs+h);
    float4 r;
    r.x = w.x*a0.x + w.y*a1.x + w.z*a2.x + w.w*a3.x + sg*as.x;
    r.y = w.x*a0.y + w.y*a1.y + w.z*a2.y + w.w*a3.y + sg*as.y;
    r.z = w.x*a0.z + w.y*a1.z + w.z*a2.z + w.w*a3.z + sg*as.z;
    r.w = w.x*a0.w + w.y*a1.w + w.z*a2.w + w.w*a3.w + sg*as.w;
    *(float4*)(o+h) = r;
  }
}

extern "C" void kernel_launch(void* const* d_in, const int* in_sizes, int n_in,
                              void* d_out, int out_size, void* d_ws, size_t ws_size,
                              hipStream_t stream)
{
  const float* x         = (const float*)d_in[0];
  const float* router_w  = (const float*)d_in[1];
  const float* gate_w    = (const float*)d_in[2];
  const float* up_w      = (const float*)d_in[3];
  const float* down_w    = (const float*)d_in[4];
  const float* sh_gate_w = (const float*)d_in[5];
  const float* sh_up_w   = (const float*)d_in[6];
  const float* sh_down_w = (const float*)d_in[7];
  const float* eg_w      = (const float*)d_in[8];

  char* p = (char*)d_ws;
  auto alloc = [&](size_t bytes)->char*{
    char* r = p; p += (bytes + 255) & ~(size_t)255; return r;
  };
  int*   counts   = (int*)  alloc(NEXP*4);
  int*   fill     = (int*)  alloc(NEXP*4);
  int*   offsets  = (int*)  alloc((NEXP+1)*4);
  int*   topk_idx = (int*)  alloc(NSLOTS*4);
  float* topk_w   = (float*)alloc(NSLOTS*4);
  int*   slot_of  = (int*)  alloc(NSLOTS*4);
  float* gates    = (float*)alloc(TOKENS*4);
  __hip_bfloat16* xb    = (__hip_bfloat16*)alloc((size_t)TOKENS*HDIM*2);
  __hip_bfloat16* xg    = (__hip_bfloat16*)alloc((size_t)(NSLOTS+ROWPAD)*HDIM*2);
  __hip_bfloat16* act   = (__hip_bfloat16*)alloc((size_t)(NSLOTS+ROWPAD)*IDIM*2);
  __hip_bfloat16* shact = (__hip_bfloat16*)alloc((size_t)TOKENS*SIDIM*2);
  float* dslot  = (float*)alloc((size_t)NSLOTS*HDIM*4);
  float* shdown = (float*)alloc((size_t)TOKENS*HDIM*4);
  if ((size_t)(p - (char*)d_ws) > ws_size) return;

  hipMemsetAsync(counts, 0, NEXP*4, stream);
  hipMemsetAsync(fill,   0, NEXP*4, stream);

  router_kernel <<<TOKENS, 64, 0, stream>>>(x, router_w, eg_w, topk_idx, topk_w, gates, counts);
  prefix_kernel <<<1, 64, 0, stream>>>(counts, offsets);
  scatter_kernel<<<TOKENS, 256, 0, stream>>>(x, topk_idx, offsets, fill, slot_of, xg, xb);

  // combined gate+up: 8 XCDs x (44 shared-quarters + 165 expert) = 1672 blocks
  gateup_all<<<1672, 256, 40*1024, stream>>>(
      gate_w, up_w, xg, act,
      sh_gate_w, sh_up_w, xb, shact, offsets);

  // combined down: 8 XCDs x (16 shared-quarters + 240 expert) = 2048 blocks
  down_all<<<2048, 256, 24*1024, stream>>>(
      down_w, act, dslot,
      sh_down_w, shact, shdown, offsets);

  combine_kernel<<<TOKENS, 256, 0, stream>>>(dslot, shdown, slot_of, topk_w, gates, (float*)d_out);
}

// Round 9
// 647.703 us; speedup vs baseline: 1.5331x; 1.1527x over previous
//
#include <hip/hip_runtime.h>
#include <hip/hip_bf16.h>
#include <stdint.h>

#define TOKENS 512
#define HDIM   2048
#define IDIM   1408
#define SIDIM  5632
#define NEXP   60
#define TOPK   4
#define NSLOTS (TOKENS*TOPK)   /* 2048 */
#define ROWPAD 64

// counted-vmcnt barrier primitives (T3/T4): raw s_barrier, NO vmcnt(0) drain
#define VMWAIT(N) asm volatile("s_waitcnt vmcnt(" #N ")" ::: "memory")
#define SBAR()    asm volatile("s_barrier" ::: "memory")

typedef __attribute__((ext_vector_type(8))) short bf16x8;
typedef __attribute__((ext_vector_type(4))) float f32x4;

__device__ __forceinline__ short f2bf(float f){
  uint32_t u = __float_as_uint(f);
  u = (u + 0x7fffu + ((u >> 16) & 1u)) >> 16;   // RNE
  return (short)(u & 0xffffu);
}

__device__ __forceinline__ bf16x8 pack8(float4 a, float4 b){
  bf16x8 r;
  r[0]=f2bf(a.x); r[1]=f2bf(a.y); r[2]=f2bf(a.z); r[3]=f2bf(a.w);
  r[4]=f2bf(b.x); r[5]=f2bf(b.y); r[6]=f2bf(b.z); r[7]=f2bf(b.w);
  return r;
}

__device__ __forceinline__ bf16x8 as_bf16x8(float4 v){
  union { float4 f; bf16x8 b; } u; u.f = v; return u.b;
}

__device__ __forceinline__ f32x4 zero4(){
  f32x4 z; z[0]=0.f; z[1]=0.f; z[2]=0.f; z[3]=0.f; return z;
}

__device__ __forceinline__ f32x4 mfma16(bf16x8 a, bf16x8 b, f32x4 c){
  return __builtin_amdgcn_mfma_f32_16x16x32_bf16(a, b, c, 0, 0, 0);
}

// ================== K-step-32 staged tiles (rule #21 both-sides swizzle) =====
// W tile: 64 rows x 32 fp32 = 8 KB = [64][8] float4 units, units rotated by
// row&7 (physical pu holds logical (pu-row)&7). LDS dest linear (HW), the
// permutation rides on the per-lane GLOBAL src. 2 loads/thread.
// (measured R5: SQ_LDS_BANK_CONFLICT == 0 with this scheme)
__device__ __forceinline__ void stage_w32(float4* tile, const float* __restrict__ W,
                                          int K, int k0, int tid){
  int l = tid & 63, wv = tid >> 6;
  #pragma unroll
  for (int j=0;j<2;j++){
    int u0 = j*256 + wv*64;                 // wave-uniform
    int u  = u0 + l;
    int row = u >> 3;
    int lu  = ((u & 7) - (row & 7)) & 7;
    const float* src = W + (size_t)row*K + k0 + lu*4;
    __builtin_amdgcn_global_load_lds(
        (const __attribute__((address_space(1))) void*)src,
        (__attribute__((address_space(3))) void*)(tile + u0), 16, 0, 0);
  }
}

// one B-fragment (8 bf16 = k kq*8..+8 of row r)
__device__ __forceinline__ bf16x8 read_wfrag32(const float4* tile, int r, int kq){
  int rot = r & 7;
  const float4* row = tile + (size_t)r*8;
  float4 f0 = row[(2*kq     + rot) & 7];
  float4 f1 = row[(2*kq + 1 + rot) & 7];
  return pack8(f0, f1);
}

// A tile: 64 rows x 32 bf16 = 4 KB = [64][4] float4 units, rotated by row&3.
// 1 load/thread.
__device__ __forceinline__ void stage_a32(float4* tile, const short* __restrict__ Arows,
                                          int K, int k0, int tid){
  int l = tid & 63, wv = tid >> 6;
  int u0 = wv*64;
  int u  = u0 + l;
  int row = u >> 2;
  int lu  = ((u & 3) - (row & 3)) & 3;
  const short* src = Arows + (size_t)row*K + k0 + lu*8;
  __builtin_amdgcn_global_load_lds(
      (const __attribute__((address_space(1))) void*)src,
      (__attribute__((address_space(3))) void*)(tile + u0), 16, 0, 0);
}

__device__ __forceinline__ void read_afrag32(const float4* tile, int c16, int kq,
                                             bf16x8* av){
  #pragma unroll
  for (int mf=0; mf<4; mf++){
    int row = c16 + 16*mf;
    av[mf] = as_bf16x8(tile[(size_t)row*4 + ((kq + row) & 3)]);
  }
}

// ---------------- router ------------------------------------------------------
__global__ __launch_bounds__(64) void router_kernel(
    const float* __restrict__ x, const float* __restrict__ rw,
    const float* __restrict__ egw, int* __restrict__ topk_idx,
    float* __restrict__ topk_w, float* __restrict__ gates,
    int* __restrict__ counts)
{
  int t = blockIdx.x;
  int lane = threadIdx.x;
  const float* xr = x + (size_t)t*HDIM;
  float xv[HDIM/64];
  #pragma unroll
  for (int i=0;i<HDIM/64;i++) xv[i] = xr[lane + 64*i];

  float mylogit = -1e30f;
  for (int e=0;e<NEXP;e++){
    const float* w = rw + (size_t)e*HDIM;
    float acc = 0.f;
    #pragma unroll
    for (int i=0;i<HDIM/64;i++) acc += xv[i]*w[lane+64*i];
    #pragma unroll
    for (int s=32;s>0;s>>=1) acc += __shfl_xor(acc, s);
    if (lane == e) mylogit = acc;
  }
  {
    float acc = 0.f;
    #pragma unroll
    for (int i=0;i<HDIM/64;i++) acc += xv[i]*egw[lane+64*i];
    #pragma unroll
    for (int s=32;s>0;s>>=1) acc += __shfl_xor(acc, s);
    if (lane == 0) gates[t] = 1.f/(1.f + __expf(-acc));
  }
  float m = mylogit;
  #pragma unroll
  for (int s=32;s>0;s>>=1) m = fmaxf(m, __shfl_xor(m, s));
  float p = (lane < NEXP) ? __expf(mylogit - m) : 0.f;
  float sum = p;
  #pragma unroll
  for (int s=32;s>0;s>>=1) sum += __shfl_xor(sum, s);
  float prob = p / sum;
  for (int k=0;k<TOPK;k++){
    float v = prob; int idx = lane;
    #pragma unroll
    for (int s=32;s>0;s>>=1){
      float ov = __shfl_xor(v, s); int oi = __shfl_xor(idx, s);
      if (ov > v || (ov == v && oi < idx)){ v = ov; idx = oi; }
    }
    if (lane == 0){
      topk_idx[t*TOPK+k] = idx;
      topk_w[t*TOPK+k]  = v;
      atomicAdd(&counts[idx], 1);
    }
    if (lane == idx) prob = -1e30f;
  }
}

__global__ void prefix_kernel(const int* __restrict__ counts, int* __restrict__ offsets)
{
  if (threadIdx.x == 0){
    int acc = 0;
    for (int e=0;e<NEXP;e++){ offsets[e] = acc; acc += counts[e]; }
    offsets[NEXP] = acc;
  }
}

__global__ __launch_bounds__(256) void scatter_kernel(
    const float* __restrict__ x, const int* __restrict__ topk_idx,
    const int* __restrict__ offsets, int* __restrict__ fill,
    int* __restrict__ slot_of, __hip_bfloat16* __restrict__ xg,
    __hip_bfloat16* __restrict__ xb)
{
  int t = blockIdx.x, tid = threadIdx.x;
  __shared__ int sl[TOPK];
  if (tid == 0){
    for (int k=0;k<TOPK;k++){
      int e = topk_idx[t*TOPK+k];
      int pos = atomicAdd(&fill[e], 1);
      int s = offsets[e] + pos;
      slot_of[t*TOPK+k] = s;
      sl[k] = s;
    }
  }
  __syncthreads();
  const float4* xr = (const float4*)(x + (size_t)t*HDIM);
  float4 v0 = xr[tid*2], v1 = xr[tid*2+1];
  bf16x8 b = pack8(v0, v1);
  *(bf16x8*)((short*)xb + (size_t)t*HDIM + tid*8) = b;
  #pragma unroll
  for (int k=0;k<TOPK;k++)
    *(bf16x8*)((short*)xg + (size_t)sl[k]*HDIM + tid*8) = b;
}

// =============== combined gate+up GEMM — R5 EXACT (control arm) ==============
// grid = 2024 blocks (8 XCDs x 253). per-XCD: pos<88 -> shared (m-tile=xcd),
// else expert q = xcd*165 + pos-88, e=q/22, bx=q%22 (same-expert contiguous).
// LDS 40 KB: G0,G1,U0,U1 (8 KB) + A0,A1 (4 KB) -> 4 blocks/CU. VMWAIT(5).
__global__ __launch_bounds__(256, 4) void gateup_all(
    const float* __restrict__ gW_e, const float* __restrict__ uW_e,
    const __hip_bfloat16* __restrict__ A_e, __hip_bfloat16* __restrict__ out_e,
    const float* __restrict__ gW_s, const float* __restrict__ uW_s,
    const __hip_bfloat16* __restrict__ A_s, __hip_bfloat16* __restrict__ out_s,
    const int* __restrict__ offsets)
{
  extern __shared__ __align__(16) char smem[];
  float4* G0 = (float4*)smem;
  float4* G1 = G0 + 512;
  float4* U0 = G1 + 512;
  float4* U1 = U0 + 512;
  float4* A0 = U1 + 512;
  float4* A1 = A0 + 256;

  int bid = blockIdx.x;
  int xcd = bid & 7, pos = bid >> 3;
  const float *Wg, *Wu; const short *Abase; short *outp;
  int NI, bx, m_start, m_end;
  if (pos < 88){                       // shared expert
    bx = pos;
    Wg = gW_s; Wu = uW_s; Abase = (const short*)A_s; outp = (short*)out_s;
    NI = SIDIM;
    m_start = xcd*64; m_end = m_start + 64;
  } else {                             // routed experts
    int q = xcd*165 + (pos - 88);
    int e = q/22; bx = q - e*22;
    size_t wo = (size_t)e * IDIM * HDIM;
    Wg = gW_e + wo; Wu = uW_e + wo;
    Abase = (const short*)A_e; outp = (short*)out_e;
    NI = IDIM;
    m_start = offsets[e]; m_end = offsets[e+1];
  }
  if (m_start >= m_end) return;
  const int K = HDIM;

  int tid  = threadIdx.x;
  int lane = tid & 63;
  int wv   = tid >> 6;
  int c16 = lane & 15, kq = lane >> 4;
  int wrow = bx*64 + wv*16 + c16;
  int r    = wv*16 + c16;
  const float* WgT = Wg + (size_t)(bx*64)*K;
  const float* WuT = Wu + (size_t)(bx*64)*K;

  for (int m0 = m_start; m0 < m_end; m0 += 64){
    int mrem = m_end - m0;
    const short* Ar = Abase + (size_t)m0*K;
    f32x4 accg[4], accu[4];
    #pragma unroll
    for (int i=0;i<4;i++){ accg[i] = zero4(); accu[i] = zero4(); }

    stage_w32(G0, WgT, K, 0, tid);
    stage_w32(U0, WuT, K, 0, tid);
    stage_a32(A0, Ar,  K, 0, tid);

    for (int k0 = 0; k0 < K; k0 += 64){
      stage_w32(G1, WgT, K, k0+32, tid);
      stage_w32(U1, WuT, K, k0+32, tid);
      stage_a32(A1, Ar,  K, k0+32, tid);
      VMWAIT(5); SBAR();
      {
        bf16x8 av[4];
        read_afrag32(A0, c16, kq, av);
        bf16x8 bg = read_wfrag32(G0, r, kq);
        bf16x8 bu = read_wfrag32(U0, r, kq);
        #pragma unroll
        for (int mf=0; mf<4; mf++){
          accg[mf] = mfma16(av[mf], bg, accg[mf]);
          accu[mf] = mfma16(av[mf], bu, accu[mf]);
        }
      }
      SBAR();
      if (k0 + 64 < K){
        stage_w32(G0, WgT, K, k0+64, tid);
        stage_w32(U0, WuT, K, k0+64, tid);
        stage_a32(A0, Ar,  K, k0+64, tid);
        VMWAIT(5);
      } else {
        VMWAIT(0);
      }
      SBAR();
      {
        bf16x8 av[4];
        read_afrag32(A1, c16, kq, av);
        bf16x8 bg = read_wfrag32(G1, r, kq);
        bf16x8 bu = read_wfrag32(U1, r, kq);
        #pragma unroll
        for (int mf=0; mf<4; mf++){
          accg[mf] = mfma16(av[mf], bg, accg[mf]);
          accu[mf] = mfma16(av[mf], bu, accu[mf]);
        }
      }
      SBAR();
    }

    #pragma unroll
    for (int mf=0; mf<4; mf++){
      #pragma unroll
      for (int j=0;j<4;j++){
        int mrow = mf*16 + kq*4 + j;
        if (mrow < mrem){
          float g = accg[mf][j], u = accu[mf][j];
          float s = g * u / (1.f + __expf(-g));
          outp[(size_t)(m0+mrow)*NI + wrow] = f2bf(s);
        }
      }
    }
  }
}

// =============== combined down GEMM — 3-DEEP PIPELINE (test arm) =============
// grid = 2176 blocks (8 x 272). per-XCD: pos<32 -> shared (m-tile=xcd,
// K=SIDIM, heavy: first), else expert q = xcd*240+pos-32, e=q/32.
// LDS 36 KB: W slots x3 (8 KB) + A slots x3 (4 KB) -> 4 blocks/CU.
// Ledger: stage tile t+2, VMWAIT(6) => tile t landed, t+1 AND t+2 in flight
// (2 tiles = 24 KB/block outstanding after the wait, 2x the R5 down depth).
__global__ __launch_bounds__(256, 4) void down_all(
    const float* __restrict__ W_e, const __hip_bfloat16* __restrict__ A_e,
    float* __restrict__ out_e,
    const float* __restrict__ W_s, const __hip_bfloat16* __restrict__ A_s,
    float* __restrict__ out_s,
    const int* __restrict__ offsets)
{
  extern __shared__ __align__(16) char smem[];
  float4* Wb = (float4*)smem;          // 3 x 512 float4
  float4* Ab = Wb + 3*512;             // 3 x 256 float4

  int bid = blockIdx.x;
  int xcd = bid & 7, pos = bid >> 3;
  const float* W; const short* Abase; float* outp;
  int K, bx, m_start, m_end;
  if (pos < 32){                       // shared expert (long blocks first)
    bx = pos;
    W = W_s; Abase = (const short*)A_s; outp = out_s; K = SIDIM;
    m_start = xcd*64; m_end = m_start + 64;
  } else {
    int q = xcd*240 + (pos - 32);
    int e = q >> 5; bx = q & 31;
    W = W_e + (size_t)e * HDIM * IDIM;
    Abase = (const short*)A_e; outp = out_e; K = IDIM;
    m_start = offsets[e]; m_end = offsets[e+1];
  }
  if (m_start >= m_end) return;

  int tid  = threadIdx.x;
  int lane = tid & 63;
  int wv   = tid >> 6;
  int c16 = lane & 15, kq = lane >> 4;
  int wrow = bx*64 + wv*16 + c16;
  int r    = wv*16 + c16;
  const float* WT = W + (size_t)(bx*64)*K;
  int np = K >> 5;                     // phases of 32 k-floats

  for (int m0 = m_start; m0 < m_end; m0 += 64){
    int mrem = m_end - m0;
    const short* Ar = Abase + (size_t)m0*K;
    f32x4 acc[4];
    #pragma unroll
    for (int i=0;i<4;i++) acc[i] = zero4();

    // prologue: tiles 0 and 1 in flight (6 loads/thread)
    stage_w32(Wb,       WT, K, 0,  tid);
    stage_a32(Ab,       Ar, K, 0,  tid);
    stage_w32(Wb + 512, WT, K, 32, tid);
    stage_a32(Ab + 256, Ar, K, 32, tid);

    int cs = 0, ss = 2;                // compute slot (p%3), stage slot ((p+2)%3)
    for (int p = 0; p < np; ++p){
      if (p + 2 < np){
        stage_w32(Wb + ss*512, WT, K, (p+2) << 5, tid);
        stage_a32(Ab + ss*256, Ar, K, (p+2) << 5, tid);
        VMWAIT(6);                     // tile p landed; p+1, p+2 in flight
      } else if (p + 1 < np){
        VMWAIT(3);                     // tile p landed; p+1 in flight
      } else {
        VMWAIT(0);                     // last tile
      }
      SBAR();
      {
        bf16x8 av[4];
        read_afrag32(Ab + cs*256, c16, kq, av);
        bf16x8 b = read_wfrag32(Wb + cs*512, r, kq);
        #pragma unroll
        for (int mf=0; mf<4; mf++)
          acc[mf] = mfma16(av[mf], b, acc[mf]);
      }
      SBAR();                          // all reads of slot cs done before restage
      cs = (cs == 2) ? 0 : cs + 1;
      ss = (ss == 2) ? 0 : ss + 1;
    }

    #pragma unroll
    for (int mf=0; mf<4; mf++){
      #pragma unroll
      for (int j=0;j<4;j++){
        int mrow = mf*16 + kq*4 + j;
        if (mrow < mrem)
          outp[(size_t)(m0+mrow)*HDIM + wrow] = acc[mf][j];
      }
    }
  }
}

// ---------------- final combine ----------------------------------------------
__global__ __launch_bounds__(256) void combine_kernel(
    const float* __restrict__ dslot, const float* __restrict__ shdown,
    const int* __restrict__ slot_of, const float* __restrict__ topw,
    const float* __restrict__ gates, float* __restrict__ out)
{
  int t = blockIdx.x, tid = threadIdx.x;
  int4  sl = ((const int4*)slot_of)[t];
  float4 w = ((const float4*)topw)[t];
  float sg = gates[t];
  const float* r0 = dslot + (size_t)sl.x*HDIM;
  const float* r1 = dslot + (size_t)sl.y*HDIM;
  const float* r2 = dslot + (size_t)sl.z*HDIM;
  const float* r3 = dslot + (size_t)sl.w*HDIM;
  const float* rs = shdown + (size_t)t*HDIM;
  float* o = out + (size_t)t*HDIM;
  #pragma unroll
  for (int it=0; it<HDIM/(256*4); ++it){
    int h = (tid + it*256) * 4;
    float4 a0 = *(const float4*)(r0+h);
    float4 a1 = *(const float4*)(r1+h);
    float4 a2 = *(const float4*)(r2+h);
    float4 a3 = *(const float4*)(r3+h);
    float4 as = *(const float4*)(rs+h);
    float4 r;
    r.x = w.x*a0.x + w.y*a1.x + w.z*a2.x + w.w*a3.x + sg*as.x;
    r.y = w.x*a0.y + w.y*a1.y + w.z*a2.y + w.w*a3.y + sg*as.y;
    r.z = w.x*a0.z + w.y*a1.z + w.z*a2.z + w.w*a3.z + sg*as.z;
    r.w = w.x*a0.w + w.y*a1.w + w.z*a2.w + w.w*a3.w + sg*as.w;
    *(float4*)(o+h) = r;
  }
}

extern "C" void kernel_launch(void* const* d_in, const int* in_sizes, int n_in,
                              void* d_out, int out_size, void* d_ws, size_t ws_size,
                              hipStream_t stream)
{
  const float* x         = (const float*)d_in[0];
  const float* router_w  = (const float*)d_in[1];
  const float* gate_w    = (const float*)d_in[2];
  const float* up_w      = (const float*)d_in[3];
  const float* down_w    = (const float*)d_in[4];
  const float* sh_gate_w = (const float*)d_in[5];
  const float* sh_up_w   = (const float*)d_in[6];
  const float* sh_down_w = (const float*)d_in[7];
  const float* eg_w      = (const float*)d_in[8];

  char* p = (char*)d_ws;
  auto alloc = [&](size_t bytes)->char*{
    char* r = p; p += (bytes + 255) & ~(size_t)255; return r;
  };
  int*   counts   = (int*)  alloc(NEXP*4);
  int*   fill     = (int*)  alloc(NEXP*4);
  int*   offsets  = (int*)  alloc((NEXP+1)*4);
  int*   topk_idx = (int*)  alloc(NSLOTS*4);
  float* topk_w   = (float*)alloc(NSLOTS*4);
  int*   slot_of  = (int*)  alloc(NSLOTS*4);
  float* gates    = (float*)alloc(TOKENS*4);
  __hip_bfloat16* xb    = (__hip_bfloat16*)alloc((size_t)TOKENS*HDIM*2);
  __hip_bfloat16* xg    = (__hip_bfloat16*)alloc((size_t)(NSLOTS+ROWPAD)*HDIM*2);
  __hip_bfloat16* act   = (__hip_bfloat16*)alloc((size_t)(NSLOTS+ROWPAD)*IDIM*2);
  __hip_bfloat16* shact = (__hip_bfloat16*)alloc((size_t)TOKENS*SIDIM*2);
  float* dslot  = (float*)alloc((size_t)NSLOTS*HDIM*4);
  float* shdown = (float*)alloc((size_t)TOKENS*HDIM*4);
  if ((size_t)(p - (char*)d_ws) > ws_size) return;

  hipMemsetAsync(counts, 0, NEXP*4, stream);
  hipMemsetAsync(fill,   0, NEXP*4, stream);

  router_kernel <<<TOKENS, 64, 0, stream>>>(x, router_w, eg_w, topk_idx, topk_w, gates, counts);
  prefix_kernel <<<1, 64, 0, stream>>>(counts, offsets);
  scatter_kernel<<<TOKENS, 256, 0, stream>>>(x, topk_idx, offsets, fill, slot_of, xg, xb);

  // combined gate+up: 8 XCDs x (88 shared + 165 expert) = 2024 blocks (R5 exact)
  gateup_all<<<2024, 256, 40*1024, stream>>>(
      gate_w, up_w, xg, act,
      sh_gate_w, sh_up_w, xb, shact, offsets);

  // combined down: 8 XCDs x (32 shared + 240 expert) = 2176 blocks, 3-deep
  down_all<<<2176, 256, 36*1024, stream>>>(
      down_w, act, dslot,
      sh_down_w, shact, shdown, offsets);

  combine_kernel<<<TOKENS, 256, 0, stream>>>(dslot, shdown, slot_of, topk_w, gates, (float*)d_out);
}